// Round 1
// baseline (39573.508 us; speedup 1.0000x reference)
//
#include <hip/hip_runtime.h>

constexpr int   HD      = 128;
constexpr float T_NEAR  = 0.2f;
constexpr float T_FAR   = 2.0f;
constexpr float ALPHA_C = 100.0f;
constexpr int   MARCH_N = 32;
constexpr float HIT_EPS = 0.005f;
constexpr int   TP_N    = 32;
constexpr float RANDU_C = 0.5f;

__device__ __forceinline__ void fma4(float4& a, float s, const float4 w) {
  a.x = fmaf(s, w.x, a.x);
  a.y = fmaf(s, w.y, a.y);
  a.z = fmaf(s, w.z, a.z);
  a.w = fmaf(s, w.w, a.w);
}

// Full SDF MLP eval for one point (one thread = one ray).
// W2 comes from LDS (wave-uniform broadcast float4 reads); W1/b1/b2/W3 are
// wave-uniform global reads (scalar-cache). h1 is computed on the fly per k
// (k-outer loop), h2 accumulated in 32 float4 registers.
__device__ float sdf_eval(float px, float py, float pz,
                          const float4* __restrict__ sW2,
                          const float* __restrict__ W1,
                          const float* __restrict__ b1,
                          const float* __restrict__ b2,
                          const float* __restrict__ W3,
                          float b3v)
{
  float4 acc[32];
  const float4* b2q = (const float4*)b2;
  #pragma unroll
  for (int j = 0; j < 32; ++j) acc[j] = b2q[j];

  #pragma unroll 2
  for (int k = 0; k < HD; ++k) {
    float h = fmaf(W1[k], px,
              fmaf(W1[HD + k], py,
              fmaf(W1[2 * HD + k], pz, b1[k])));
    h = fmaxf(h, 0.0f);
    const float4* row = sW2 + (k << 5);
    #pragma unroll
    for (int j = 0; j < 32; ++j) fma4(acc[j], h, row[j]);
  }

  float r = b3v;
  const float4* w3q = (const float4*)W3;
  #pragma unroll
  for (int j = 0; j < 32; ++j) {
    float4 a = acc[j];
    float4 w = w3q[j];
    r = fmaf(fmaxf(a.x, 0.0f), w.x, r);
    r = fmaf(fmaxf(a.y, 0.0f), w.y, r);
    r = fmaf(fmaxf(a.z, 0.0f), w.z, r);
    r = fmaf(fmaxf(a.w, 0.0f), w.w, r);
  }
  return r;
}

__global__ __launch_bounds__(256, 2)
void sdf_render_kernel(const float* __restrict__ rays,
                       const float* __restrict__ W1, const float* __restrict__ b1,
                       const float* __restrict__ W2, const float* __restrict__ b2,
                       const float* __restrict__ W3, const float* __restrict__ b3,
                       const float* __restrict__ R1, const float* __restrict__ rb1,
                       const float* __restrict__ R2, const float* __restrict__ rb2,
                       float* __restrict__ out, int nrays)
{
  // 64 KB: W2 (128x128 f32), row-major, 32 float4 per row.
  __shared__ float4 sW2[HD * 32];
  const int tid = threadIdx.x;
  const float4* W2v = (const float4*)W2;
  for (int i = tid; i < HD * 32; i += 256) sW2[i] = W2v[i];
  __syncthreads();

  const int ray = blockIdx.x * 256 + tid;
  if (ray >= nrays) return;

  const float rox = rays[ray * 6 + 0];
  const float roy = rays[ray * 6 + 1];
  const float roz = rays[ray * 6 + 2];
  const float rdx = rays[ray * 6 + 3];
  const float rdy = rays[ray * 6 + 4];
  const float rdz = rays[ray * 6 + 5];
  const float b3v = b3[0];

  // ---- sphere-march (32 iters, frozen once hit) ----
  float cd = T_NEAR;
  bool hit = false;
  for (int it = 0; it < MARCH_N; ++it) {
    float px = fmaf(rdx, cd, rox);
    float py = fmaf(rdy, cd, roy);
    float pz = fmaf(rdz, cd, roz);
    float d = sdf_eval(px, py, pz, sW2, W1, b1, b2, W3, b3v);
    bool nh = (d < HIT_EPS) && (cd >= T_NEAR) && (cd <= T_FAR);
    hit = hit || nh;
    if (!hit) cd += d;
  }

  // ---- reflectance net at final point ----
  const float ptx = fmaf(rdx, cd, rox);
  const float pty = fmaf(rdy, cd, roy);
  const float ptz = fmaf(rdz, cd, roz);
  float cr = rb2[0], cg = rb2[1], cb = rb2[2];
  for (int j = 0; j < HD; ++j) {
    float h = fmaf(R1[0 * HD + j], ptx,
              fmaf(R1[1 * HD + j], pty,
              fmaf(R1[2 * HD + j], ptz,
              fmaf(R1[3 * HD + j], rdx,
              fmaf(R1[4 * HD + j], rdy,
              fmaf(R1[5 * HD + j], rdz, rb1[j]))))));
    h = fmaxf(h, 0.0f);
    cr = fmaf(h, R2[j * 3 + 0], cr);
    cg = fmaf(h, R2[j * 3 + 1], cg);
    cb = fmaf(h, R2[j * 3 + 2], cb);
  }

  // ---- tube-point scan: argmin of sdf over 33 fixed samples ----
  constexpr float STEP = (T_FAR + RANDU_C * (2.0f / TP_N)) / TP_N;  // 0.0634765625 exact
  float mn = sdf_eval(rox, roy, roz, sW2, W1, b1, b2, W3, b3v);
  int idx = 0;
  for (int s = 1; s <= TP_N; ++s) {
    float t = STEP * (float)s;
    float px = fmaf(rdx, t, rox);
    float py = fmaf(rdy, t, roy);
    float pz = fmaf(rdz, t, roz);
    float d = sdf_eval(px, py, pz, sW2, W1, b1, b2, W3, b3v);
    if (d < mn) { mn = d; idx = s; }
  }
  const float bt = STEP * (float)idx;
  const float bx = fmaf(rdx, bt, rox);
  const float by = fmaf(rdy, bt, roy);
  const float bz = fmaf(rdz, bt, roz);
  const float tput = sdf_eval(bx, by, bz, sW2, W1, b1, b2, W3, b3v);

  float4 o;
  o.x = hit ? cr : 0.0f;
  o.y = hit ? cg : 0.0f;
  o.z = hit ? cb : 0.0f;
  o.w = -ALPHA_C * tput;
  ((float4*)out)[ray] = o;
}

extern "C" void kernel_launch(void* const* d_in, const int* in_sizes, int n_in,
                              void* d_out, int out_size, void* d_ws, size_t ws_size,
                              hipStream_t stream) {
  const float* rays = (const float*)d_in[0];
  const float* W1  = (const float*)d_in[1];
  const float* b1  = (const float*)d_in[2];
  const float* W2  = (const float*)d_in[3];
  const float* b2  = (const float*)d_in[4];
  const float* W3  = (const float*)d_in[5];
  const float* b3  = (const float*)d_in[6];
  const float* R1  = (const float*)d_in[7];
  const float* rb1 = (const float*)d_in[8];
  const float* R2  = (const float*)d_in[9];
  const float* rb2 = (const float*)d_in[10];

  const int nrays = in_sizes[0] / 6;
  dim3 grid((nrays + 255) / 256);
  dim3 block(256);
  hipLaunchKernelGGL(sdf_render_kernel, grid, block, 0, stream,
                     rays, W1, b1, W2, b2, W3, b3, R1, rb1, R2, rb2,
                     (float*)d_out, nrays);
}

// Round 2
// 9151.678 us; speedup vs baseline: 4.3242x; 4.3242x over previous
//
#include <hip/hip_runtime.h>

typedef __attribute__((ext_vector_type(8))) short bf16x8;
typedef __attribute__((ext_vector_type(4))) float f32x4;

constexpr int   HD      = 128;
constexpr float T_NEAR  = 0.2f;
constexpr float T_FAR   = 2.0f;
constexpr float ALPHA_C = 100.0f;
constexpr int   MARCH_N = 32;
constexpr float HIT_EPS = 0.005f;
constexpr int   TP_N    = 32;
constexpr float STEP    = 0.0634765625f;  // (2.0 + 0.5*(2/32))/32 exact in f32

// ---------- bf16 helpers (bit-exact RNE, no class-type unions) ----------
__device__ __forceinline__ unsigned short f2bf(float x) {
  unsigned u = __float_as_uint(x);
  unsigned r = 0x7fffu + ((u >> 16) & 1u);
  return (unsigned short)((u + r) >> 16);
}
__device__ __forceinline__ unsigned pack2(float lo, float hi) {
  return (unsigned)f2bf(lo) | ((unsigned)f2bf(hi) << 16);
}
__device__ __forceinline__ float blo(unsigned u) { return __uint_as_float(u << 16); }
__device__ __forceinline__ float bhi(unsigned u) { return __uint_as_float(u & 0xffff0000u); }

union U8 { bf16x8 v; uint4 u4; unsigned short us[8]; };

// ---------- setup kernel: pack W2^T into per-lane MFMA A-fragments ----------
// frag element (s,t,lane,j): A[m=16t+(lane&15)][k=32s+(lane>>4)*8+j] = W2[k*128+m]
// hi = bf16(w), lo = bf16(w - f32(hi)).  16384 elements each.
__global__ void pack_w2(const float* __restrict__ W2,
                        unsigned short* __restrict__ hi,
                        unsigned short* __restrict__ lo) {
  int idx = blockIdx.x * 256 + threadIdx.x;     // 0..16383
  int j = idx & 7, l = (idx >> 3) & 63, t = (idx >> 9) & 7, s = idx >> 12;
  int m = 16 * t + (l & 15);
  int k = 32 * s + (l >> 4) * 8 + j;
  float w = W2[k * HD + m];
  unsigned short h = f2bf(w);
  float hf = __uint_as_float(((unsigned)h) << 16);
  hi[idx] = h;
  lo[idx] = f2bf(w - hf);
}

// ---------- bf16 MFMA SDF eval: returns d for lane's ray (all lanes) ----------
__device__ __forceinline__ float sdf_mfma(
    float tval, const bf16x8 (&w2f)[4][8],
    const uint4* __restrict__ sac, int tid,
    const unsigned (&w3u)[16], const unsigned (&b2u)[16], float b3v)
{
  f32x4 acc[8];
  #pragma unroll
  for (int t = 0; t < 8; ++t) acc[t] = (f32x4){0.f, 0.f, 0.f, 0.f};

  #pragma unroll
  for (int s = 0; s < 4; ++s) {
    uint4 av = sac[s * 256 + tid];
    uint4 cv = sac[(4 + s) * 256 + tid];
    float h0 = fmaxf(fmaf(blo(cv.x), tval, blo(av.x)), 0.f);
    float h1 = fmaxf(fmaf(bhi(cv.x), tval, bhi(av.x)), 0.f);
    float h2 = fmaxf(fmaf(blo(cv.y), tval, blo(av.y)), 0.f);
    float h3 = fmaxf(fmaf(bhi(cv.y), tval, bhi(av.y)), 0.f);
    float h4 = fmaxf(fmaf(blo(cv.z), tval, blo(av.z)), 0.f);
    float h5 = fmaxf(fmaf(bhi(cv.z), tval, bhi(av.z)), 0.f);
    float h6 = fmaxf(fmaf(blo(cv.w), tval, blo(av.w)), 0.f);
    float h7 = fmaxf(fmaf(bhi(cv.w), tval, bhi(av.w)), 0.f);
    U8 b;
    b.u4.x = pack2(h0, h1); b.u4.y = pack2(h2, h3);
    b.u4.z = pack2(h4, h5); b.u4.w = pack2(h6, h7);
    #pragma unroll
    for (int t = 0; t < 8; ++t)
      acc[t] = __builtin_amdgcn_mfma_f32_16x16x32_bf16(w2f[s][t], b.v, acc[t], 0, 0, 0);
  }

  float d = 0.f;
  #pragma unroll
  for (int t = 0; t < 8; ++t) {
    unsigned ba = b2u[t * 2], bb = b2u[t * 2 + 1];
    unsigned wa = w3u[t * 2], wb = w3u[t * 2 + 1];
    d = fmaf(fmaxf(acc[t][0] + blo(ba), 0.f), blo(wa), d);
    d = fmaf(fmaxf(acc[t][1] + bhi(ba), 0.f), bhi(wa), d);
    d = fmaf(fmaxf(acc[t][2] + blo(bb), 0.f), blo(wb), d);
    d = fmaf(fmaxf(acc[t][3] + bhi(bb), 0.f), bhi(wb), d);
  }
  d += __shfl_xor(d, 16);
  d += __shfl_xor(d, 32);
  return d + b3v;
}

// ---------- hi/lo-split high-precision eval (for the x100 tput channel) ----------
__device__ __forceinline__ float sdf_precise(
    float tval, int q, int lane,
    float rox, float roy, float roz, float rdx, float rdy, float rdz,
    const float* __restrict__ W1, const float* __restrict__ b1,
    const bf16x8 (&w2f)[4][8], const unsigned short* __restrict__ wlo,
    const float* __restrict__ W3, const float* __restrict__ b2, float b3v)
{
  f32x4 acc[8];
  #pragma unroll
  for (int t = 0; t < 8; ++t) acc[t] = (f32x4){0.f, 0.f, 0.f, 0.f};

  const bf16x8* wloF = (const bf16x8*)wlo;
  #pragma unroll
  for (int s = 0; s < 4; ++s) {
    int kb = 32 * s + q * 8;
    U8 hh, hl;
    #pragma unroll
    for (int j = 0; j < 8; ++j) {
      int k = kb + j;
      float w1x = W1[k], w1y = W1[HD + k], w1z = W1[2 * HD + k];
      float a = fmaf(w1x, rox, fmaf(w1y, roy, fmaf(w1z, roz, b1[k])));
      float c = fmaf(w1x, rdx, fmaf(w1y, rdy, w1z * rdz));
      float h = fmaxf(fmaf(c, tval, a), 0.f);
      unsigned short hb = f2bf(h);
      float hf = __uint_as_float(((unsigned)hb) << 16);
      hh.us[j] = hb;
      hl.us[j] = f2bf(h - hf);
    }
    #pragma unroll
    for (int t = 0; t < 8; ++t) {
      bf16x8 wl = wloF[(s * 8 + t) * 64 + lane];
      acc[t] = __builtin_amdgcn_mfma_f32_16x16x32_bf16(w2f[s][t], hh.v, acc[t], 0, 0, 0);
      acc[t] = __builtin_amdgcn_mfma_f32_16x16x32_bf16(wl,       hh.v, acc[t], 0, 0, 0);
      acc[t] = __builtin_amdgcn_mfma_f32_16x16x32_bf16(w2f[s][t], hl.v, acc[t], 0, 0, 0);
    }
  }

  float d = 0.f;
  #pragma unroll
  for (int t = 0; t < 8; ++t) {
    #pragma unroll
    for (int r = 0; r < 4; ++r) {
      int n = 16 * t + q * 4 + r;
      d = fmaf(fmaxf(acc[t][r] + b2[n], 0.f), W3[n], d);
    }
  }
  d += __shfl_xor(d, 16);
  d += __shfl_xor(d, 32);
  return d + b3v;
}

// ---------- main kernel: 1 wave = 16 rays, block = 4 waves = 64 rays ----------
__global__ __launch_bounds__(256, 2)
void render(const float* __restrict__ rays,
            const float* __restrict__ W1, const float* __restrict__ b1,
            const float* __restrict__ b2, const float* __restrict__ W3,
            const float* __restrict__ b3,
            const float* __restrict__ R1, const float* __restrict__ rb1,
            const float* __restrict__ R2, const float* __restrict__ rb2,
            const unsigned short* __restrict__ whi,
            const unsigned short* __restrict__ wlo,
            float* __restrict__ out, int nrays)
{
  // per-THREAD private a/c staging: chunk c (0..7, 16B) at sac[c*256+tid].
  // No cross-thread sharing -> no barrier needed.
  __shared__ uint4 sac[8 * 256];
  const int tid  = threadIdx.x;
  const int lane = tid & 63;
  const int q    = lane >> 4;
  const int wv   = tid >> 6;
  const int ray  = blockIdx.x * 64 + wv * 16 + (lane & 15);

  // resident W2^T hi fragments: 32 frags x 4 VGPR = 128 VGPRs
  bf16x8 w2f[4][8];
  const bf16x8* whiF = (const bf16x8*)whi;
  #pragma unroll
  for (int s = 0; s < 4; ++s)
    #pragma unroll
    for (int t = 0; t < 8; ++t)
      w2f[s][t] = whiF[(s * 8 + t) * 64 + lane];

  const float rox = rays[ray * 6 + 0];
  const float roy = rays[ray * 6 + 1];
  const float roz = rays[ray * 6 + 2];
  const float rdx = rays[ray * 6 + 3];
  const float rdy = rays[ray * 6 + 4];
  const float rdz = rays[ray * 6 + 5];
  const float b3v = b3[0];

  // a[k] = W1^T ro + b1, c[k] = W1^T rd for this lane's 32 k's; bf16-packed to LDS
  #pragma unroll
  for (int s = 0; s < 4; ++s) {
    int kb = 32 * s + q * 8;
    float a[8], c[8];
    #pragma unroll
    for (int j = 0; j < 8; ++j) {
      int k = kb + j;
      float w1x = W1[k], w1y = W1[HD + k], w1z = W1[2 * HD + k];
      a[j] = fmaf(w1x, rox, fmaf(w1y, roy, fmaf(w1z, roz, b1[k])));
      c[j] = fmaf(w1x, rdx, fmaf(w1y, rdy, w1z * rdz));
    }
    uint4 ua, uc;
    ua.x = pack2(a[0], a[1]); ua.y = pack2(a[2], a[3]);
    ua.z = pack2(a[4], a[5]); ua.w = pack2(a[6], a[7]);
    uc.x = pack2(c[0], c[1]); uc.y = pack2(c[2], c[3]);
    uc.z = pack2(c[4], c[5]); uc.w = pack2(c[6], c[7]);
    sac[s * 256 + tid] = ua;
    sac[(4 + s) * 256 + tid] = uc;
  }

  // resident packed W3/b2 for this lane's 32 output indices n = 16t + q*4 + r
  unsigned w3u[16], b2u[16];
  #pragma unroll
  for (int t = 0; t < 8; ++t) {
    int n0 = 16 * t + q * 4;
    w3u[t * 2]     = pack2(W3[n0],     W3[n0 + 1]);
    w3u[t * 2 + 1] = pack2(W3[n0 + 2], W3[n0 + 3]);
    b2u[t * 2]     = pack2(b2[n0],     b2[n0 + 1]);
    b2u[t * 2 + 1] = pack2(b2[n0 + 2], b2[n0 + 3]);
  }

  // ---- sphere march ----
  float cd = T_NEAR;
  bool hit = false;
  for (int it = 0; it < MARCH_N; ++it) {
    float d = sdf_mfma(cd, w2f, sac, tid, w3u, b2u, b3v);
    bool nh = (d < HIT_EPS) && (cd >= T_NEAR) && (cd <= T_FAR);
    hit = hit || nh;
    cd = hit ? cd : cd + d;
  }

  // ---- reflectance (exact fp32), split over 4 lane-quads ----
  const float ptx = fmaf(rdx, cd, rox);
  const float pty = fmaf(rdy, cd, roy);
  const float ptz = fmaf(rdz, cd, roz);
  float cr = 0.f, cg = 0.f, cb = 0.f;
  {
    int jb = q * 32;
    for (int jj = 0; jj < 32; ++jj) {
      int j = jb + jj;
      float h = fmaf(R1[0 * HD + j], ptx,
                fmaf(R1[1 * HD + j], pty,
                fmaf(R1[2 * HD + j], ptz,
                fmaf(R1[3 * HD + j], rdx,
                fmaf(R1[4 * HD + j], rdy,
                fmaf(R1[5 * HD + j], rdz, rb1[j]))))));
      h = fmaxf(h, 0.f);
      cr = fmaf(h, R2[j * 3 + 0], cr);
      cg = fmaf(h, R2[j * 3 + 1], cg);
      cb = fmaf(h, R2[j * 3 + 2], cb);
    }
    cr += __shfl_xor(cr, 16); cr += __shfl_xor(cr, 32);
    cg += __shfl_xor(cg, 16); cg += __shfl_xor(cg, 32);
    cb += __shfl_xor(cb, 16); cb += __shfl_xor(cb, 32);
    cr += rb2[0]; cg += rb2[1]; cb += rb2[2];
  }

  // ---- tube scan: argmin over t = 0, STEP, 2*STEP, ..., 32*STEP ----
  float mn = sdf_mfma(0.f, w2f, sac, tid, w3u, b2u, b3v);
  int idx = 0;
  for (int s = 1; s <= TP_N; ++s) {
    float t = STEP * (float)s;
    float d = sdf_mfma(t, w2f, sac, tid, w3u, b2u, b3v);
    if (d < mn) { mn = d; idx = s; }
  }

  // ---- final tput at best_pos, hi/lo split (~fp32 quality) ----
  const float tb = STEP * (float)idx;
  const float tput = sdf_precise(tb, q, lane, rox, roy, roz, rdx, rdy, rdz,
                                 W1, b1, w2f, wlo, W3, b2, b3v);

  if (q == 0) {
    float4 o;
    o.x = hit ? cr : 0.f;
    o.y = hit ? cg : 0.f;
    o.z = hit ? cb : 0.f;
    o.w = -ALPHA_C * tput;
    ((float4*)out)[ray] = o;
  }
}

extern "C" void kernel_launch(void* const* d_in, const int* in_sizes, int n_in,
                              void* d_out, int out_size, void* d_ws, size_t ws_size,
                              hipStream_t stream) {
  const float* rays = (const float*)d_in[0];
  const float* W1  = (const float*)d_in[1];
  const float* b1  = (const float*)d_in[2];
  const float* W2  = (const float*)d_in[3];
  const float* b2  = (const float*)d_in[4];
  const float* W3  = (const float*)d_in[5];
  const float* b3  = (const float*)d_in[6];
  const float* R1  = (const float*)d_in[7];
  const float* rb1 = (const float*)d_in[8];
  const float* R2  = (const float*)d_in[9];
  const float* rb2 = (const float*)d_in[10];

  unsigned short* whi = (unsigned short*)d_ws;            // 32 KB
  unsigned short* wlo = whi + 128 * 128;                  // 32 KB

  const int nrays = in_sizes[0] / 6;

  hipLaunchKernelGGL(pack_w2, dim3(64), dim3(256), 0, stream, W2, whi, wlo);
  hipLaunchKernelGGL(render, dim3(nrays / 64), dim3(256), 0, stream,
                     rays, W1, b1, b2, W3, b3, R1, rb1, R2, rb2,
                     whi, wlo, (float*)d_out, nrays);
}

// Round 3
// 3404.569 us; speedup vs baseline: 11.6236x; 2.6881x over previous
//
#include <hip/hip_runtime.h>

typedef __attribute__((ext_vector_type(8))) short bf16x8;
typedef __attribute__((ext_vector_type(4))) float f32x4;
typedef __attribute__((ext_vector_type(2))) float f32x2;

constexpr int   HD      = 128;
constexpr float T_NEAR  = 0.2f;
constexpr float T_FAR   = 2.0f;
constexpr float ALPHA_C = 100.0f;
constexpr int   MARCH_N = 32;
constexpr float HIT_EPS = 0.005f;
constexpr int   TP_N    = 32;
constexpr float STEP    = 0.0634765625f;  // (2.0 + 0.5*(2/32))/32, exact

// ---------- bf16 helpers ----------
__device__ __forceinline__ unsigned short f2bf(float x) {
  unsigned u = __float_as_uint(x);
  unsigned r = 0x7fffu + ((u >> 16) & 1u);
  return (unsigned short)((u + r) >> 16);
}

union U8 { bf16x8 v; uint4 u4; unsigned short us[8]; };

// packed fp32 fma: d = a*b + c (VOP3P, 1 instr for 2 floats)
__device__ __forceinline__ f32x2 pk_fma(f32x2 a, f32x2 b, f32x2 c) {
  f32x2 d;
  asm("v_pk_fma_f32 %0, %1, %2, %3" : "=v"(d) : "v"(a), "v"(b), "v"(c));
  return d;
}

// {h.x,h.y} -> packed bf16 pair (round-half-up) with relu applied in bf16-bit
// domain (max_i16 vs 0 zeroes any negative bf16; sign-exact).
__device__ __forceinline__ unsigned pack_relu_pair(f32x2 h) {
  unsigned u0 = __float_as_uint(h.x) + 0x8000u;
  unsigned u1 = __float_as_uint(h.y) + 0x8000u;
  unsigned w, r;
  asm("v_perm_b32 %0, %1, %2, %3" : "=v"(w) : "v"(u1), "v"(u0), "s"(0x07060302u));
  asm("v_pk_max_i16 %0, %1, %2" : "=v"(r) : "v"(w), "v"(0u));
  return r;
}

// ---------- setup kernel: pack W2^T into per-lane MFMA A-fragments ----------
// A[m=16t+(lane&15)][k=32s+(lane>>4)*8+j] = W2[k*128+m]; hi + residual lo.
__global__ void pack_w2(const float* __restrict__ W2,
                        unsigned short* __restrict__ hi,
                        unsigned short* __restrict__ lo) {
  int idx = blockIdx.x * 256 + threadIdx.x;     // 0..16383
  int j = idx & 7, l = (idx >> 3) & 63, t = (idx >> 9) & 7, s = idx >> 12;
  int m = 16 * t + (l & 15);
  int k = 32 * s + (l >> 4) * 8 + j;
  float w = W2[k * HD + m];
  unsigned short h = f2bf(w);
  float hf = __uint_as_float(((unsigned)h) << 16);
  hi[idx] = h;
  lo[idx] = f2bf(w - hf);
}

// ---------- fast bf16 MFMA SDF eval (register-only) ----------
__device__ __forceinline__ float sdf_fast(float t,
    const bf16x8 (&w2f)[4][8], const f32x2 (&ap)[16], const f32x2 (&cp)[16],
    const f32x4 (&b2f)[8], const f32x2 (&w3p)[16], float b3v)
{
  f32x2 t2; t2.x = t; t2.y = t;
  U8 B[4];
  #pragma unroll
  for (int s = 0; s < 4; ++s) {
    unsigned w0 = pack_relu_pair(pk_fma(cp[4*s+0], t2, ap[4*s+0]));
    unsigned w1 = pack_relu_pair(pk_fma(cp[4*s+1], t2, ap[4*s+1]));
    unsigned w2 = pack_relu_pair(pk_fma(cp[4*s+2], t2, ap[4*s+2]));
    unsigned w3 = pack_relu_pair(pk_fma(cp[4*s+3], t2, ap[4*s+3]));
    uint4 u; u.x = w0; u.y = w1; u.z = w2; u.w = w3;
    B[s].u4 = u;
  }

  f32x4 acc[8];
  #pragma unroll
  for (int u = 0; u < 8; ++u)   // b2 folded in as C operand (zero extra ops)
    acc[u] = __builtin_amdgcn_mfma_f32_16x16x32_bf16(w2f[0][u], B[0].v, b2f[u], 0, 0, 0);
  #pragma unroll
  for (int s = 1; s < 4; ++s)
    #pragma unroll
    for (int u = 0; u < 8; ++u)
      acc[u] = __builtin_amdgcn_mfma_f32_16x16x32_bf16(w2f[s][u], B[s].v, acc[u], 0, 0, 0);

  f32x2 e0; e0.x = 0.f; e0.y = 0.f;
  f32x2 e1 = e0, e2 = e0, e3 = e0;
  #pragma unroll
  for (int u = 0; u < 8; ++u) {
    f32x4 y = acc[u];
    f32x2 lo; lo.x = fmaxf(y.x, 0.f); lo.y = fmaxf(y.y, 0.f);
    f32x2 hi; hi.x = fmaxf(y.z, 0.f); hi.y = fmaxf(y.w, 0.f);
    if (u & 1) { e2 = pk_fma(lo, w3p[2*u], e2); e3 = pk_fma(hi, w3p[2*u+1], e3); }
    else       { e0 = pk_fma(lo, w3p[2*u], e0); e1 = pk_fma(hi, w3p[2*u+1], e1); }
  }
  float d = (e0.x + e0.y) + (e1.x + e1.y) + ((e2.x + e2.y) + (e3.x + e3.y));
  d += __shfl_xor(d, 16);
  d += __shfl_xor(d, 32);
  return d + b3v;
}

// ---------- hi/lo-split precise eval (for the x100 tput channel) ----------
__device__ float sdf_precise(float t, int lane,
    const bf16x8 (&w2f)[4][8], const f32x2 (&ap)[16], const f32x2 (&cp)[16],
    const f32x4 (&b2f)[8], const f32x2 (&w3p)[16], float b3v,
    const unsigned short* __restrict__ wlo)
{
  U8 HH[4], HL[4];
  #pragma unroll
  for (int s = 0; s < 4; ++s) {
    #pragma unroll
    for (int p = 0; p < 4; ++p) {
      float h0 = fmaxf(fmaf(cp[4*s+p].x, t, ap[4*s+p].x), 0.f);
      float h1 = fmaxf(fmaf(cp[4*s+p].y, t, ap[4*s+p].y), 0.f);
      unsigned short hb0 = f2bf(h0), hb1 = f2bf(h1);
      float r0 = h0 - __uint_as_float(((unsigned)hb0) << 16);
      float r1 = h1 - __uint_as_float(((unsigned)hb1) << 16);
      HH[s].us[2*p]     = hb0;      HH[s].us[2*p + 1] = hb1;
      HL[s].us[2*p]     = f2bf(r0); HL[s].us[2*p + 1] = f2bf(r1);
    }
  }

  const bf16x8* wloF = (const bf16x8*)wlo;
  f32x4 acc[8];
  #pragma unroll
  for (int u = 0; u < 8; ++u)
    acc[u] = __builtin_amdgcn_mfma_f32_16x16x32_bf16(w2f[0][u], HH[0].v, b2f[u], 0, 0, 0);
  #pragma unroll
  for (int s = 0; s < 4; ++s) {
    #pragma unroll
    for (int u = 0; u < 8; ++u) {
      bf16x8 wl = wloF[(s * 8 + u) * 64 + lane];
      if (s > 0)
        acc[u] = __builtin_amdgcn_mfma_f32_16x16x32_bf16(w2f[s][u], HH[s].v, acc[u], 0, 0, 0);
      acc[u] = __builtin_amdgcn_mfma_f32_16x16x32_bf16(wl, HH[s].v, acc[u], 0, 0, 0);
      acc[u] = __builtin_amdgcn_mfma_f32_16x16x32_bf16(w2f[s][u], HL[s].v, acc[u], 0, 0, 0);
    }
  }

  f32x2 e0; e0.x = 0.f; e0.y = 0.f;
  f32x2 e1 = e0, e2 = e0, e3 = e0;
  #pragma unroll
  for (int u = 0; u < 8; ++u) {
    f32x4 y = acc[u];
    f32x2 lo; lo.x = fmaxf(y.x, 0.f); lo.y = fmaxf(y.y, 0.f);
    f32x2 hi; hi.x = fmaxf(y.z, 0.f); hi.y = fmaxf(y.w, 0.f);
    if (u & 1) { e2 = pk_fma(lo, w3p[2*u], e2); e3 = pk_fma(hi, w3p[2*u+1], e3); }
    else       { e0 = pk_fma(lo, w3p[2*u], e0); e1 = pk_fma(hi, w3p[2*u+1], e1); }
  }
  float d = (e0.x + e0.y) + (e1.x + e1.y) + ((e2.x + e2.y) + (e3.x + e3.y));
  d += __shfl_xor(d, 16);
  d += __shfl_xor(d, 32);
  return d + b3v;
}

// ---------- main: 1 wave = 16 rays; 1 wave/SIMD by design (no spills) ----------
__global__ __launch_bounds__(256, 1)
void render(const float* __restrict__ rays,
            const float* __restrict__ W1, const float* __restrict__ b1,
            const float* __restrict__ b2, const float* __restrict__ W3,
            const float* __restrict__ b3,
            const float* __restrict__ R1, const float* __restrict__ rb1,
            const float* __restrict__ R2, const float* __restrict__ rb2,
            const unsigned short* __restrict__ whi,
            const unsigned short* __restrict__ wlo,
            float* __restrict__ out, int nrays)
{
  const int tid  = threadIdx.x;
  const int lane = tid & 63;
  const int q    = lane >> 4;
  const int wv   = tid >> 6;
  const int ray  = blockIdx.x * 64 + wv * 16 + (lane & 15);

  // W2^T hi fragments resident: 128 VGPRs
  bf16x8 w2f[4][8];
  const bf16x8* whiF = (const bf16x8*)whi;
  #pragma unroll
  for (int s = 0; s < 4; ++s)
    #pragma unroll
    for (int u = 0; u < 8; ++u)
      w2f[s][u] = whiF[(s * 8 + u) * 64 + lane];

  const float rox = rays[ray * 6 + 0];
  const float roy = rays[ray * 6 + 1];
  const float roz = rays[ray * 6 + 2];
  const float rdx = rays[ray * 6 + 3];
  const float rdy = rays[ray * 6 + 4];
  const float rdz = rays[ray * 6 + 5];
  const float b3v = b3[0];

  // a[k] = W1^T ro + b1, c[k] = W1^T rd  (fp32, register-resident, pair-packed)
  f32x2 ap[16], cp[16];
  #pragma unroll
  for (int s = 0; s < 4; ++s)
    #pragma unroll
    for (int p = 0; p < 4; ++p) {
      int k0 = 32 * s + 8 * q + 2 * p;
      int k1 = k0 + 1;
      float x0 = W1[k0], y0 = W1[HD + k0], z0 = W1[2 * HD + k0];
      float x1 = W1[k1], y1 = W1[HD + k1], z1 = W1[2 * HD + k1];
      f32x2 a, c;
      a.x = fmaf(x0, rox, fmaf(y0, roy, fmaf(z0, roz, b1[k0])));
      a.y = fmaf(x1, rox, fmaf(y1, roy, fmaf(z1, roz, b1[k1])));
      c.x = fmaf(x0, rdx, fmaf(y0, rdy, z0 * rdz));
      c.y = fmaf(x1, rdx, fmaf(y1, rdy, z1 * rdz));
      ap[4 * s + p] = a;
      cp[4 * s + p] = c;
    }

  // b2 as MFMA C-init fragments; W3 as fp32 pairs
  f32x4 b2f[8];
  f32x2 w3p[16];
  #pragma unroll
  for (int u = 0; u < 8; ++u) {
    int n0 = 16 * u + 4 * q;
    f32x4 bb; bb.x = b2[n0]; bb.y = b2[n0 + 1]; bb.z = b2[n0 + 2]; bb.w = b2[n0 + 3];
    b2f[u] = bb;
    f32x2 wa; wa.x = W3[n0];     wa.y = W3[n0 + 1];
    f32x2 wb; wb.x = W3[n0 + 2]; wb.y = W3[n0 + 3];
    w3p[2 * u] = wa; w3p[2 * u + 1] = wb;
  }

  // ---- sphere march (serial; break when all 16 rays hit) ----
  float cd = T_NEAR;
  bool hit = false;
  #pragma unroll 1
  for (int it = 0; it < MARCH_N; ++it) {
    float d = sdf_fast(cd, w2f, ap, cp, b2f, w3p, b3v);
    bool nh = (d < HIT_EPS) && (cd >= T_NEAR) && (cd <= T_FAR);
    hit = hit || nh;
    cd = hit ? cd : cd + d;
    if (__ballot(!hit) == 0ull) break;
  }

  // ---- reflectance (exact fp32), split over 4 lane-quads ----
  const float ptx = fmaf(rdx, cd, rox);
  const float pty = fmaf(rdy, cd, roy);
  const float ptz = fmaf(rdz, cd, roz);
  float cr = 0.f, cg = 0.f, cb = 0.f;
  {
    int jb = q * 32;
    #pragma unroll 1
    for (int jj = 0; jj < 32; ++jj) {
      int j = jb + jj;
      float h = fmaf(R1[0 * HD + j], ptx,
                fmaf(R1[1 * HD + j], pty,
                fmaf(R1[2 * HD + j], ptz,
                fmaf(R1[3 * HD + j], rdx,
                fmaf(R1[4 * HD + j], rdy,
                fmaf(R1[5 * HD + j], rdz, rb1[j]))))));
      h = fmaxf(h, 0.f);
      cr = fmaf(h, R2[j * 3 + 0], cr);
      cg = fmaf(h, R2[j * 3 + 1], cg);
      cb = fmaf(h, R2[j * 3 + 2], cb);
    }
    cr += __shfl_xor(cr, 16); cr += __shfl_xor(cr, 32);
    cg += __shfl_xor(cg, 16); cg += __shfl_xor(cg, 32);
    cb += __shfl_xor(cb, 16); cb += __shfl_xor(cb, 32);
    cr += rb2[0]; cg += rb2[1]; cb += rb2[2];
  }

  // ---- tube scan: argmin of sdf over t = s*STEP, s = 0..32 ----
  float mn = sdf_fast(0.f, w2f, ap, cp, b2f, w3p, b3v);
  int idx = 0;
  float ts = 0.f;
  #pragma unroll 1
  for (int s = 1; s <= TP_N; ++s) {
    ts += STEP;                       // exact (65*s/1024, s<=32)
    float d = sdf_fast(ts, w2f, ap, cp, b2f, w3p, b3v);
    if (d < mn) { mn = d; idx = s; }
  }

  // ---- final tput at best t, hi/lo split ----
  const float tb = STEP * (float)idx;
  const float tput = sdf_precise(tb, lane, w2f, ap, cp, b2f, w3p, b3v, wlo);

  if (q == 0) {
    float4 o;
    o.x = hit ? cr : 0.f;
    o.y = hit ? cg : 0.f;
    o.z = hit ? cb : 0.f;
    o.w = -ALPHA_C * tput;
    ((float4*)out)[ray] = o;
  }
}

extern "C" void kernel_launch(void* const* d_in, const int* in_sizes, int n_in,
                              void* d_out, int out_size, void* d_ws, size_t ws_size,
                              hipStream_t stream) {
  const float* rays = (const float*)d_in[0];
  const float* W1  = (const float*)d_in[1];
  const float* b1  = (const float*)d_in[2];
  const float* W2  = (const float*)d_in[3];
  const float* b2  = (const float*)d_in[4];
  const float* W3  = (const float*)d_in[5];
  const float* b3  = (const float*)d_in[6];
  const float* R1  = (const float*)d_in[7];
  const float* rb1 = (const float*)d_in[8];
  const float* R2  = (const float*)d_in[9];
  const float* rb2 = (const float*)d_in[10];

  unsigned short* whi = (unsigned short*)d_ws;   // 32 KB
  unsigned short* wlo = whi + 128 * 128;         // 32 KB

  const int nrays = in_sizes[0] / 6;

  hipLaunchKernelGGL(pack_w2, dim3(64), dim3(256), 0, stream, W2, whi, wlo);
  hipLaunchKernelGGL(render, dim3(nrays / 64), dim3(256), 0, stream,
                     rays, W1, b1, b2, W3, b3, R1, rb1, R2, rb2,
                     whi, wlo, (float*)d_out, nrays);
}